// Round 1
// 511.729 us; speedup vs baseline: 1.5478x; 1.5478x over previous
//
#include <hip/hip_runtime.h>

#define VOCAB 10000
#define EMB 64
#define HID 128
#define BATCH 32
#define TT 256
#define M_TOK (BATCH * TT)   // 8192 tokens
#define NPAD 10112           // 79 * 128, zero-padded vocab rows
#define KP 136               // padded LDS row stride in ushorts (136*2=272B, 16B aligned)

typedef float f32x4 __attribute__((ext_vector_type(4)));
typedef float f32x2 __attribute__((ext_vector_type(2)));
typedef short s16x8 __attribute__((ext_vector_type(8)));

__device__ inline unsigned f2bf(float x) {
  unsigned u = __float_as_uint(x);
  return (u + 0x7fffu + ((u >> 16) & 1u)) >> 16;  // round-to-nearest-even
}

// Inline branch-free tanh: no libcall -> u[] can live in VGPRs across it.
__device__ inline float tanh_fast(float x) {
  float ax = __builtin_fabsf(x);
  float t = __builtin_amdgcn_exp2f(-2.885390082f * ax);  // e^{-2|x|}  (2*log2 e)
  float r = __builtin_amdgcn_rcpf(1.0f + t);
  float y = (1.0f - t) * r;
  return __builtin_copysignf(y, x);
}

// ---------------- kernel 1: xw[tok][j] = emb[ids[tok]] @ W + b ----------------
__global__ void k_embed_xw(const int* __restrict__ ids, const float* __restrict__ emb,
                           const float* __restrict__ W, const float* __restrict__ bias,
                           float* __restrict__ xw) {
  __shared__ float er[EMB];
  int tok = blockIdx.x, j = threadIdx.x;
  int id = ids[tok];
  if (j < EMB) er[j] = emb[(long)id * EMB + j];
  __syncthreads();
  float acc = bias[j];
#pragma unroll
  for (int e = 0; e < EMB; ++e) acc = fmaf(er[e], W[e * HID + j], acc);
  xw[tok * HID + j] = acc;
}

// ---------------- kernel 2: WdT[n][k] = bf16(Wd[k][n]), zero-padded to NPAD rows ----
__global__ void k_wdt(const float* __restrict__ Wd, ushort* __restrict__ WdT) {
  __shared__ float tile[64][HID + 1];  // 33 KB, +1 pad breaks bank conflicts
  int n0 = blockIdx.x * 64;
  int t = threadIdx.x;
  int nn = t & 63, kbase = t >> 6;  // 256 threads: 64 n x 4 k per iter
#pragma unroll 4
  for (int it = 0; it < 32; ++it) {
    int k = it * 4 + kbase;
    int n = n0 + nn;
    float v = (n < VOCAB) ? Wd[k * VOCAB + n] : 0.0f;  // coalesced along n
    tile[nn][k] = v;
  }
  __syncthreads();
  int k2 = (t & 63) * 2, row = t >> 6;
#pragma unroll 4
  for (int it = 0; it < 16; ++it) {
    int nn2 = it * 4 + row;
    unsigned pa = f2bf(tile[nn2][k2]);
    unsigned pb = f2bf(tile[nn2][k2 + 1]);
    ((unsigned*)WdT)[(n0 + nn2) * (HID / 2) + (t & 63)] = pa | (pb << 16);  // coalesced
  }
}

// ---------------- kernel 3: fp32 RNN scan, one block per batch ----------------
// h_t = tanh(xw_t + h_{t-1} @ U); U column j lives in 128 VGPRs of thread j.
// v2: (a) whole xw[b] (128 KB) staged to LDS up front via global_load_lds ->
//     no global loads in the recurrence loop; (b) raw s_barrier with
//     lgkmcnt(0)-only wait -> the per-step hout store and any global traffic
//     stay in flight across the barrier (old __syncthreads forced vmcnt(0)
//     = store-confirm + cross-XCD load latency exposed every step);
//     (c) f32x2 accumulators to coax v_pk_fma_f32 (halve VALU issue).
__global__ void __launch_bounds__(HID, 1) k_scan(const float* __restrict__ xw,
                                                 const float* __restrict__ U,
                                                 ushort* __restrict__ hout) {
  __shared__ __align__(16) float xs[TT * HID];   // 128 KB: all xw for this batch
  __shared__ __align__(16) float hbuf[2][HID];   // double-buffered h
  const int b = blockIdx.x, j = threadIdx.x;

  // ---- stage xw[b] -> LDS, 64 calls x (128 lanes x 16B) = 2 KB/call ----
  const float* src = xw + (long)b * TT * HID;
#pragma unroll
  for (int it = 0; it < 64; ++it) {
    __builtin_amdgcn_global_load_lds(
        (const __attribute__((address_space(1))) void*)(src + it * 512 + j * 4),
        (__attribute__((address_space(3))) void*)(xs + it * 512 + j * 4),
        16, 0, 0);
  }

  // ---- U column j -> 128 VGPRs (as 64 f32x2 pairs), coalesced loads ----
  f32x2 u2[64];
#pragma unroll
  for (int i = 0; i < 64; ++i) {
    u2[i].x = U[(2 * i + 0) * HID + j];
    u2[i].y = U[(2 * i + 1) * HID + j];
  }
  hbuf[0][j] = 0.0f;

  asm volatile("s_waitcnt vmcnt(0) lgkmcnt(0)" ::: "memory");  // staging done
  __builtin_amdgcn_s_barrier();
  __builtin_amdgcn_sched_barrier(0);

  ushort* hob = hout + (long)b * TT * HID + j;
  int p = 0;
  for (int t = 0; t < TT; ++t) {
    float xv = xs[t * HID + j];  // LDS read; latency hidden under FMA chain
    f32x2 a0 = {0.f, 0.f}, a1 = {0.f, 0.f}, a2 = {0.f, 0.f}, a3 = {0.f, 0.f};
    const float4* h4 = (const float4*)hbuf[p];
#pragma unroll
    for (int i = 0; i < HID / 8; ++i) {
      float4 hva = h4[2 * i + 0];  // ds_read_b128 broadcast
      float4 hvb = h4[2 * i + 1];
      f32x2 ha0; ha0.x = hva.x; ha0.y = hva.y;
      f32x2 ha1; ha1.x = hva.z; ha1.y = hva.w;
      f32x2 hb0; hb0.x = hvb.x; hb0.y = hvb.y;
      f32x2 hb1; hb1.x = hvb.z; hb1.y = hvb.w;
      a0 += ha0 * u2[4 * i + 0];
      a1 += ha1 * u2[4 * i + 1];
      a2 += hb0 * u2[4 * i + 2];
      a3 += hb1 * u2[4 * i + 3];
    }
    f32x2 s2 = (a0 + a1) + (a2 + a3);
    float h = tanh_fast(s2.x + s2.y + xv);
    hbuf[1 - p][j] = h;                 // ds_write to the other buffer
    hob[t * HID] = (ushort)f2bf(h);     // fire-and-forget global store
    p ^= 1;
    // barrier protects LDS only: wait lgkm (own ds_write retired), NOT vmcnt.
    asm volatile("s_waitcnt lgkmcnt(0)" ::: "memory");
    __builtin_amdgcn_s_barrier();
    __builtin_amdgcn_sched_barrier(0);
  }
}

// ---------------- kernel 4: out = rnn_bf16 [8192x128] @ Wd_bf16 [128x10000] + bd ----
__global__ void __launch_bounds__(256, 2) k_gemm(const ushort* __restrict__ A,
                                                 const ushort* __restrict__ Bt,
                                                 const float* __restrict__ bd,
                                                 float* __restrict__ out) {
  __shared__ ushort As[128 * KP];  // 34 KB, rows [m][k]
  __shared__ ushort Bs[128 * KP];  // 34 KB, rows [n][k]
  int m0 = blockIdx.x * 128, n0 = blockIdx.y * 128;
  int t = threadIdx.x;
  // stage A and Bt: 128 rows x 256 B each, 16B vector copies
#pragma unroll
  for (int it = 0; it < 8; ++it) {
    int c = it * 256 + t;
    int row = c >> 4, off = c & 15;
    uint4 va = ((const uint4*)(A + (m0 + row) * HID))[off];
    *((uint4*)(As + row * KP + off * 8)) = va;
    uint4 vb = ((const uint4*)(Bt + (n0 + row) * HID))[off];
    *((uint4*)(Bs + row * KP + off * 8)) = vb;
  }
  __syncthreads();

  int lane = t & 63, w = t >> 6;
  int wm = (w >> 1) * 64, wn = (w & 1) * 64;  // 4 waves -> 2x2 of 64x64 tiles
  int fm = lane & 15, kq = lane >> 4;

  f32x4 acc[4][4];
#pragma unroll
  for (int mt = 0; mt < 4; ++mt)
#pragma unroll
    for (int nt = 0; nt < 4; ++nt) acc[mt][nt] = (f32x4){0.f, 0.f, 0.f, 0.f};

#pragma unroll
  for (int ks = 0; ks < 4; ++ks) {
    s16x8 af[4], bf[4];
#pragma unroll
    for (int mt = 0; mt < 4; ++mt)
      af[mt] = *(const s16x8*)(As + (wm + mt * 16 + fm) * KP + ks * 32 + kq * 8);
#pragma unroll
    for (int nt = 0; nt < 4; ++nt)
      bf[nt] = *(const s16x8*)(Bs + (wn + nt * 16 + fm) * KP + ks * 32 + kq * 8);
#pragma unroll
    for (int mt = 0; mt < 4; ++mt)
#pragma unroll
      for (int nt = 0; nt < 4; ++nt)
        acc[mt][nt] = __builtin_amdgcn_mfma_f32_16x16x32_bf16(af[mt], bf[nt], acc[mt][nt], 0, 0, 0);
  }

  // epilogue: C/D layout col=lane&15, row=(lane>>4)*4+reg
#pragma unroll
  for (int mt = 0; mt < 4; ++mt) {
    int rbase = m0 + wm + mt * 16 + kq * 4;
#pragma unroll
    for (int nt = 0; nt < 4; ++nt) {
      int col = n0 + wn + nt * 16 + fm;
      if (col < VOCAB) {
        float bdv = bd[col];
#pragma unroll
        for (int r = 0; r < 4; ++r)
          out[(long)(rbase + r) * VOCAB + col] = acc[mt][nt][r] + bdv;
      }
    }
  }
}

extern "C" void kernel_launch(void* const* d_in, const int* in_sizes, int n_in,
                              void* d_out, int out_size, void* d_ws, size_t ws_size,
                              hipStream_t stream) {
  const int* ids = (const int*)d_in[0];
  const float* emb = (const float*)d_in[1];
  const float* W = (const float*)d_in[2];
  const float* U = (const float*)d_in[3];
  const float* b = (const float*)d_in[4];
  const float* Wd = (const float*)d_in[5];
  const float* bd = (const float*)d_in[6];
  float* out = (float*)d_out;

  char* ws = (char*)d_ws;
  float* xw = (float*)ws;                            // 8192*128*4 = 4 MB
  ushort* hbf = (ushort*)(ws + 4u * 1024 * 1024);    // 8192*128*2 = 2 MB
  ushort* wdt = (ushort*)(ws + 6u * 1024 * 1024);    // 10112*128*2 = 2.59 MB

  k_embed_xw<<<dim3(M_TOK), dim3(HID), 0, stream>>>(ids, emb, W, b, xw);
  k_wdt<<<dim3(NPAD / 64), dim3(256), 0, stream>>>(Wd, wdt);
  k_scan<<<dim3(BATCH), dim3(HID), 0, stream>>>(xw, U, hbf);
  k_gemm<<<dim3(M_TOK / 128, NPAD / 128), dim3(256), 0, stream>>>(hbf, wdt, bd, out);
}